// Round 3
// baseline (2459.820 us; speedup 1.0000x reference)
//
#include <hip/hip_runtime.h>

// Problem constants (fixed by the reference)
#define N_TOKENS 32768
#define N_CODES  8192
#define DIM      512

// GEMM tiling: BM tokens per block, BN-code tiles, BK k-chunks
#define BM 64
#define BN 128
#define BK 64

// Output layout (FP32 elements, concatenated in reference return order:
// z_q_st [32768,512], vq_loss, commitment_loss, indices [32768])
#define OUT_VQ     16777216
#define OUT_COMMIT 16777217
#define OUT_IDX    16777218

typedef _Float16 f16x8 __attribute__((ext_vector_type(8)));
typedef _Float16 f16x4 __attribute__((ext_vector_type(4)));
typedef float    f32x4 __attribute__((ext_vector_type(4)));

// XOR-swizzled LDS index (in halves) for element (row, k-group of 8 halves).
// Row stride 64 halves (128 B); every access 16B-aligned; frag reads are
// <=2-way bank-aliased (free per m136), staging writes conflict-free.
__device__ __forceinline__ int sw_idx(int row, int kgrp) {
    return row * 64 + ((kgrp ^ (row & 7)) << 3);
}

// ---------------------------------------------------------------------------
// Kernel 1: codebook squared norms + zero the loss accumulator.
// ws usage: nc fp32[8192] @ byte 0, accum fp32 @ byte 32768. Total 32772 B.
__global__ void vq_norms_kernel(const float* __restrict__ cb,
                                float* __restrict__ nc,
                                float* __restrict__ accum) {
    if (blockIdx.x == 0 && threadIdx.x == 0) *accum = 0.0f;
    const int wid  = threadIdx.x >> 6;
    const int lane = threadIdx.x & 63;
    const int code = blockIdx.x * 4 + wid;
    const float4* row = (const float4*)(cb + (size_t)code * DIM);
    float s = 0.0f;
#pragma unroll
    for (int i = 0; i < 2; ++i) {
        float4 v = row[lane + i * 64];
        s += v.x * v.x + v.y * v.y + v.z * v.z + v.w * v.w;
    }
#pragma unroll
    for (int off = 32; off > 0; off >>= 1) s += __shfl_down(s, off);
    if (lane == 0) nc[code] = s;
}

// ---------------------------------------------------------------------------
// Kernel 2: fused 3-pass f16-split GEMM + argmin + gather + loss.
// Grid: 512 blocks x 256 threads (4 waves, 2x2 wave grid). Each wave computes
// a 32x64 slice of the 64x128 score tile. After the code sweep the block
// reduces per-token argmin in LDS, then cooperatively gathers codebook rows
// and writes fp32 z_q + fp32 indices + one atomicAdd loss partial.
__global__ __launch_bounds__(256, 2)
void vq_main_kernel(const float* __restrict__ z_e,
                    const float* __restrict__ cb,
                    const float* __restrict__ nc,
                    float* __restrict__ out,
                    float* __restrict__ accum) {
    // LDS: As_hi 8K | As_lo 8K | Bs_hi 16K | Bs_lo 16K = 48 KB
    __shared__ __align__(16) unsigned char smem[49152];
    _Float16* As_hi = (_Float16*)(smem);
    _Float16* As_lo = (_Float16*)(smem + 8192);
    _Float16* Bs_hi = (_Float16*)(smem + 16384);
    _Float16* Bs_lo = (_Float16*)(smem + 32768);

    const int tid    = threadIdx.x;
    const int wid    = tid >> 6;
    const int lane   = tid & 63;
    const int wave_m = wid >> 1;   // 0..1 : 32-row half of the A tile
    const int wave_n = wid & 1;    // 0..1 : 64-col half of the B tile
    const int lane15 = lane & 15;
    const int quad   = lane >> 4;  // 0..3

    const int block_row0 = blockIdx.x * BM;

    // per-lane running argmin over rows wave_m*32 + mi*16 + quad*4 + r
    float minv[2][4];
    int   mini[2][4];
#pragma unroll
    for (int mi = 0; mi < 2; ++mi)
#pragma unroll
        for (int r = 0; r < 4; ++r) { minv[mi][r] = __builtin_inff(); mini[mi][r] = 0; }

    // staging coordinates: 256 threads = 16 rows x 16 float4-groups per pass
    const int s_r0 = tid >> 4;   // 0..15
    const int s_cg = tid & 15;   // float4 group within 64-k chunk

#pragma unroll 1
    for (int nt = 0; nt < N_CODES / BN; ++nt) {
        f32x4 acc[2][4];
#pragma unroll
        for (int mi = 0; mi < 2; ++mi)
#pragma unroll
            for (int ni = 0; ni < 4; ++ni) acc[mi][ni] = (f32x4){0.f, 0.f, 0.f, 0.f};

        const float* cb_tile = cb + (size_t)nt * BN * DIM;

#pragma unroll 1
        for (int kc = 0; kc < DIM / BK; ++kc) {
            __syncthreads();   // protect LDS from previous chunk's readers
            // --- stage A chunk: 64 rows x 64 k, fp32 -> f16 hi/lo split ---
#pragma unroll
            for (int rr = 0; rr < BM / 16; ++rr) {
                const int row = rr * 16 + s_r0;
                float4 v = *(const float4*)&z_e[(size_t)(block_row0 + row) * DIM + kc * BK + s_cg * 4];
                _Float16 hx = (_Float16)v.x, hy = (_Float16)v.y, hz = (_Float16)v.z, hw = (_Float16)v.w;
                f16x4 hi = {hx, hy, hz, hw};
                f16x4 lo = {(_Float16)(v.x - (float)hx), (_Float16)(v.y - (float)hy),
                            (_Float16)(v.z - (float)hz), (_Float16)(v.w - (float)hw)};
                const int a = sw_idx(row, s_cg >> 1) + (s_cg & 1) * 4;
                *(f16x4*)&As_hi[a] = hi;
                *(f16x4*)&As_lo[a] = lo;
            }
            // --- stage B chunk: 128 rows x 64 k ---
#pragma unroll
            for (int rr = 0; rr < BN / 16; ++rr) {
                const int row = rr * 16 + s_r0;
                float4 v = *(const float4*)&cb_tile[(size_t)row * DIM + kc * BK + s_cg * 4];
                _Float16 hx = (_Float16)v.x, hy = (_Float16)v.y, hz = (_Float16)v.z, hw = (_Float16)v.w;
                f16x4 hi = {hx, hy, hz, hw};
                f16x4 lo = {(_Float16)(v.x - (float)hx), (_Float16)(v.y - (float)hy),
                            (_Float16)(v.z - (float)hz), (_Float16)(v.w - (float)hw)};
                const int a = sw_idx(row, s_cg >> 1) + (s_cg & 1) * 4;
                *(f16x4*)&Bs_hi[a] = hi;
                *(f16x4*)&Bs_lo[a] = lo;
            }
            __syncthreads();

            // --- MFMA: 2 k-steps of 32, 3 passes (hh, hl, lh) ---
#pragma unroll
            for (int ks = 0; ks < 2; ++ks) {
                const int kgrp = ks * 4 + quad;
                f16x8 ah[2], al[2], bh[4], bl[4];
#pragma unroll
                for (int mi = 0; mi < 2; ++mi) {
                    const int a = sw_idx(wave_m * 32 + mi * 16 + lane15, kgrp);
                    ah[mi] = *(const f16x8*)&As_hi[a];
                    al[mi] = *(const f16x8*)&As_lo[a];
                }
#pragma unroll
                for (int ni = 0; ni < 4; ++ni) {
                    const int b = sw_idx(wave_n * 64 + ni * 16 + lane15, kgrp);
                    bh[ni] = *(const f16x8*)&Bs_hi[b];
                    bl[ni] = *(const f16x8*)&Bs_lo[b];
                }
#pragma unroll
                for (int mi = 0; mi < 2; ++mi)
#pragma unroll
                    for (int ni = 0; ni < 4; ++ni) {
                        acc[mi][ni] = __builtin_amdgcn_mfma_f32_16x16x32_f16(ah[mi], bh[ni], acc[mi][ni], 0, 0, 0);
                        acc[mi][ni] = __builtin_amdgcn_mfma_f32_16x16x32_f16(ah[mi], bl[ni], acc[mi][ni], 0, 0, 0);
                        acc[mi][ni] = __builtin_amdgcn_mfma_f32_16x16x32_f16(al[mi], bh[ni], acc[mi][ni], 0, 0, 0);
                    }
            }
        }

        // --- score = ||c||^2 - 2*dot; update running argmin ---
#pragma unroll
        for (int ni = 0; ni < 4; ++ni) {
            const int c = nt * BN + wave_n * 64 + ni * 16 + lane15;
            const float nrm = nc[c];
#pragma unroll
            for (int mi = 0; mi < 2; ++mi)
#pragma unroll
                for (int r = 0; r < 4; ++r) {
                    const float v = fmaf(-2.0f, acc[mi][ni][r], nrm);
                    if (v < minv[mi][r]) { minv[mi][r] = v; mini[mi][r] = c; }
                }
        }
    }

    // --- cross-lane / cross-wave argmin reduction through LDS ---
    __syncthreads();
    float* redv      = (float*)smem;           // [wave_n][64 rows][16 lanes]
    int*   redi      = (int*)(smem + 8192);
    int*   final_idx = (int*)(smem + 16384);   // [64]
    float* wpart     = (float*)(smem + 16640); // [4]
#pragma unroll
    for (int mi = 0; mi < 2; ++mi)
#pragma unroll
        for (int r = 0; r < 4; ++r) {
            const int row_local = wave_m * 32 + mi * 16 + quad * 4 + r;
            const int o = wave_n * 1024 + row_local * 16 + lane15;
            redv[o] = minv[mi][r];
            redi[o] = mini[mi][r];
        }
    __syncthreads();
    if (tid < BM) {
        float bv = __builtin_inff();
        int   bi = 0;
        for (int j = 0; j < 32; ++j) {
            const int o = (j >= 16 ? 1024 : 0) + tid * 16 + (j & 15);
            const float v = redv[o];
            const int   i = redi[o];
            // jnp.argmin tie-break: lowest index wins on exact equality
            if (v < bv || (v == bv && i < bi)) { bv = v; bi = i; }
        }
        final_idx[tid] = bi;
        out[OUT_IDX + block_row0 + tid] = (float)bi;   // fp32 index output
    }
    __syncthreads();

    // --- fused gather: fp32 z_q (exact codebook rows) + loss partial ---
    float part = 0.0f;
#pragma unroll
    for (int rr = 0; rr < BM / 16; ++rr) {
        const int row  = rr * 16 + s_r0;
        const int code = final_idx[row] & (N_CODES - 1);  // defensive: always in-bounds
        const float4* zr = (const float4*)(z_e + (size_t)(block_row0 + row) * DIM);
        const float4* cr = (const float4*)(cb + (size_t)code * DIM);
        float4* orow = (float4*)out + (size_t)(block_row0 + row) * (DIM / 4);
#pragma unroll
        for (int j = 0; j < 8; ++j) {
            const int e = s_cg + j * 16;
            float4 z = zr[e];
            float4 c = cr[e];
            orow[e] = c;                                  // z_q_st value == z_q
            float dx = z.x - c.x, dy = z.y - c.y, dz = z.z - c.z, dw = z.w - c.w;
            part += dx * dx + dy * dy + dz * dz + dw * dw;
        }
    }
#pragma unroll
    for (int off = 32; off > 0; off >>= 1) part += __shfl_down(part, off);
    if (lane == 0) wpart[wid] = part;
    __syncthreads();
    if (tid == 0) atomicAdd(accum, wpart[0] + wpart[1] + wpart[2] + wpart[3]);
}

// ---------------------------------------------------------------------------
// Kernel 3: finalize losses (fp32)
__global__ void vq_finalize_kernel(const float* __restrict__ accum,
                                   float* __restrict__ out) {
    const float c = *accum * (1.0f / (float)(N_TOKENS * DIM));
    out[OUT_VQ]     = 0.25f * c;
    out[OUT_COMMIT] = c;
}

// ---------------------------------------------------------------------------
extern "C" void kernel_launch(void* const* d_in, const int* in_sizes, int n_in,
                              void* d_out, int out_size, void* d_ws, size_t ws_size,
                              hipStream_t stream) {
    const float* z_e = (const float*)d_in[0];
    const float* cb  = (const float*)d_in[1];
    float* out = (float*)d_out;

    // workspace footprint: nc fp32[8192] @0, accum fp32 @32768 -> 32772 bytes total
    float* nc    = (float*)d_ws;
    float* accum = (float*)((char*)d_ws + 32768);

    hipLaunchKernelGGL(vq_norms_kernel,    dim3(N_CODES / 4),   dim3(256), 0, stream, cb, nc, accum);
    hipLaunchKernelGGL(vq_main_kernel,     dim3(N_TOKENS / BM), dim3(256), 0, stream, z_e, cb, nc, out, accum);
    hipLaunchKernelGGL(vq_finalize_kernel, dim3(1), dim3(1), 0, stream, accum, out);
}

// Round 4
// 2169.042 us; speedup vs baseline: 1.1341x; 1.1341x over previous
//
#include <hip/hip_runtime.h>

// Problem constants (fixed by the reference)
#define N_TOKENS 32768
#define N_CODES  8192
#define DIM      512

// Tiling: 128 token-rows x 128 codes per tile, BK=64, 4 code-slices
#define BMT 128
#define BNT 128
#define SLICES 4
#define SLICE_CODES (N_CODES / SLICES)   // 2048
#define NTILES (SLICE_CODES / BNT)       // 16
#define BK 64

// Output layout (FP32 elements, reference return order)
#define OUT_VQ     16777216
#define OUT_COMMIT 16777217
#define OUT_IDX    16777218

// Workspace byte offsets: cb_hi 8MB | cb_lo 8MB | nc 32KB | partials 1MB | accum
#define WS_CBHI 0
#define WS_CBLO 8388608
#define WS_NC   16777216
#define WS_PART 16809984
#define WS_ACC  17858560   // total ~17.03 MB

typedef _Float16 f16x8 __attribute__((ext_vector_type(8)));
typedef _Float16 f16x4 __attribute__((ext_vector_type(4)));
typedef float    f32x4 __attribute__((ext_vector_type(4)));

// XOR-swizzled LDS offset (halves) for (row, kgrp of 8 halves); row stride 128B.
// Conflict-clean pattern measured in round 3 (1e6 conflicts over 50M ds_reads).
__device__ __forceinline__ int sw_idx(int row, int kgrp) {
    return row * 64 + ((kgrp ^ (row & 7)) << 3);
}

// async 16B global->LDS (lds dest = wave-uniform base + lane*16)
__device__ __forceinline__ void async_copy16(void* lds, const void* g) {
    __builtin_amdgcn_global_load_lds(
        (const __attribute__((address_space(1))) unsigned int*)g,
        (__attribute__((address_space(3))) unsigned int*)lds,
        16, 0, 0);
}

// ---------------------------------------------------------------------------
// Kernel 1: codebook -> planar f16 hi/lo split + squared norms + zero accum.
// One wave per code row; grid 2048 x 256.
__global__ void vq_prep_kernel(const float* __restrict__ cb,
                               _Float16* __restrict__ cb_hi,
                               _Float16* __restrict__ cb_lo,
                               float* __restrict__ nc,
                               float* __restrict__ accum) {
    if (blockIdx.x == 0 && threadIdx.x == 0) *accum = 0.0f;
    const int wid  = threadIdx.x >> 6;
    const int lane = threadIdx.x & 63;
    const int row  = blockIdx.x * 4 + wid;
    const float4* src = (const float4*)(cb + (size_t)row * DIM);
    float4 v0 = src[lane * 2];
    float4 v1 = src[lane * 2 + 1];
    float s = v0.x*v0.x + v0.y*v0.y + v0.z*v0.z + v0.w*v0.w
            + v1.x*v1.x + v1.y*v1.y + v1.z*v1.z + v1.w*v1.w;
    f16x8 hi = {(_Float16)v0.x, (_Float16)v0.y, (_Float16)v0.z, (_Float16)v0.w,
                (_Float16)v1.x, (_Float16)v1.y, (_Float16)v1.z, (_Float16)v1.w};
    f16x8 lo = {(_Float16)(v0.x - (float)hi[0]), (_Float16)(v0.y - (float)hi[1]),
                (_Float16)(v0.z - (float)hi[2]), (_Float16)(v0.w - (float)hi[3]),
                (_Float16)(v1.x - (float)hi[4]), (_Float16)(v1.y - (float)hi[5]),
                (_Float16)(v1.z - (float)hi[6]), (_Float16)(v1.w - (float)hi[7])};
    *(f16x8*)&cb_hi[(size_t)row * DIM + lane * 8] = hi;
    *(f16x8*)&cb_lo[(size_t)row * DIM + lane * 8] = lo;
#pragma unroll
    for (int off = 32; off > 0; off >>= 1) s += __shfl_down(s, off);
    if (lane == 0) nc[row] = s;
}

// ---------------------------------------------------------------------------
// Kernel 2: 3-plane f16-split GEMM + per-slice argmin.
// Grid (256 m-tiles, 4 code-slices) x 256 threads (2x2 waves of 64x64).
// Per k-chunk: stage A hi+lo (one fp32 read, both planes) + B hi via
// global_load_lds; passes (Ahi*Bhi + Alo*Bhi), restage B lo, pass (Ahi*Blo).
__global__ __launch_bounds__(256, 3)
void vq_main_kernel(const float* __restrict__ z_e,
                    const _Float16* __restrict__ cb_hi,
                    const _Float16* __restrict__ cb_lo,
                    const float* __restrict__ nc,
                    float2* __restrict__ partials) {
    __shared__ __align__(16) unsigned char smem[49152];
    _Float16* As_hi = (_Float16*)smem;             // 16KB: 128 rows x 64 k
    _Float16* As_lo = (_Float16*)(smem + 16384);   // 16KB
    _Float16* Bs    = (_Float16*)(smem + 32768);   // 16KB: 128 codes x 64 k

    const int tid    = threadIdx.x;
    const int wid    = tid >> 6;
    const int lane   = tid & 63;
    const int wave_m = wid >> 1;
    const int wave_n = wid & 1;
    const int lane15 = lane & 15;
    const int quad   = lane >> 4;

    const int row0 = blockIdx.x * BMT;
    const int ns   = blockIdx.y;
    const int c00  = ns * SLICE_CODES;

    float minv[4][4];
    int   mini[4][4];
#pragma unroll
    for (int mi = 0; mi < 4; ++mi)
#pragma unroll
        for (int r = 0; r < 4; ++r) { minv[mi][r] = __builtin_inff(); mini[mi][r] = 0; }

    const int s_r0 = tid >> 4;    // A staging: 16 rows x 16 float4-groups
    const int s_cg = tid & 15;
    const int b_r8 = lane >> 3;   // B staging: 8 rows x 8 kgrps per wave-load
    const int b_g  = lane & 7;

#pragma unroll 1
    for (int nt = 0; nt < NTILES; ++nt) {
        const int c0 = c00 + nt * BNT;
        f32x4 acc[4][4];
#pragma unroll
        for (int mi = 0; mi < 4; ++mi)
#pragma unroll
            for (int ni = 0; ni < 4; ++ni) acc[mi][ni] = (f32x4){0.f, 0.f, 0.f, 0.f};

#pragma unroll 1
        for (int kc = 0; kc < DIM / BK; ++kc) {
            __syncthreads();
            // --- stage B hi: 16 async wave-loads (4 per wave), inverse-swizzled src ---
#pragma unroll
            for (int i = 0; i < 4; ++i) {
                const int L = wid * 4 + i;
                const int brow = L * 8 + b_r8;
                const _Float16* g = cb_hi + (size_t)(c0 + brow) * DIM + kc * BK + ((b_g ^ (brow & 7)) << 3);
                async_copy16(Bs + L * 512, g);
            }
            // --- stage A hi+lo from one fp32 read ---
#pragma unroll
            for (int rr = 0; rr < 8; ++rr) {
                const int row = rr * 16 + s_r0;
                float4 v = *(const float4*)&z_e[(size_t)(row0 + row) * DIM + kc * BK + s_cg * 4];
                f16x4 hi = {(_Float16)v.x, (_Float16)v.y, (_Float16)v.z, (_Float16)v.w};
                f16x4 lo = {(_Float16)(v.x - (float)hi[0]), (_Float16)(v.y - (float)hi[1]),
                            (_Float16)(v.z - (float)hi[2]), (_Float16)(v.w - (float)hi[3])};
                const int a = sw_idx(row, s_cg >> 1) + ((s_cg & 1) << 2);
                *(f16x4*)&As_hi[a] = hi;
                *(f16x4*)&As_lo[a] = lo;
            }
            __syncthreads();

            // --- passes 1+2: (Ahi + Alo) x Bhi ; b-frag loaded once ---
#pragma unroll
            for (int ks = 0; ks < 2; ++ks) {
                const int kg = ks * 4 + quad;
                f16x8 bf[4], ah[4], al[4];
#pragma unroll
                for (int ni = 0; ni < 4; ++ni)
                    bf[ni] = *(const f16x8*)&Bs[sw_idx(wave_n * 64 + ni * 16 + lane15, kg)];
#pragma unroll
                for (int mi = 0; mi < 4; ++mi) {
                    const int a = sw_idx(wave_m * 64 + mi * 16 + lane15, kg);
                    ah[mi] = *(const f16x8*)&As_hi[a];
                    al[mi] = *(const f16x8*)&As_lo[a];
                }
#pragma unroll
                for (int mi = 0; mi < 4; ++mi)
#pragma unroll
                    for (int ni = 0; ni < 4; ++ni) {
                        acc[mi][ni] = __builtin_amdgcn_mfma_f32_16x16x32_f16(ah[mi], bf[ni], acc[mi][ni], 0, 0, 0);
                        acc[mi][ni] = __builtin_amdgcn_mfma_f32_16x16x32_f16(al[mi], bf[ni], acc[mi][ni], 0, 0, 0);
                    }
            }
            __syncthreads();
            // --- restage B lo ---
#pragma unroll
            for (int i = 0; i < 4; ++i) {
                const int L = wid * 4 + i;
                const int brow = L * 8 + b_r8;
                const _Float16* g = cb_lo + (size_t)(c0 + brow) * DIM + kc * BK + ((b_g ^ (brow & 7)) << 3);
                async_copy16(Bs + L * 512, g);
            }
            __syncthreads();
            // --- pass 3: Ahi x Blo ---
#pragma unroll
            for (int ks = 0; ks < 2; ++ks) {
                const int kg = ks * 4 + quad;
                f16x8 bf[4], ah[4];
#pragma unroll
                for (int ni = 0; ni < 4; ++ni)
                    bf[ni] = *(const f16x8*)&Bs[sw_idx(wave_n * 64 + ni * 16 + lane15, kg)];
#pragma unroll
                for (int mi = 0; mi < 4; ++mi)
                    ah[mi] = *(const f16x8*)&As_hi[sw_idx(wave_m * 64 + mi * 16 + lane15, kg)];
#pragma unroll
                for (int mi = 0; mi < 4; ++mi)
#pragma unroll
                    for (int ni = 0; ni < 4; ++ni)
                        acc[mi][ni] = __builtin_amdgcn_mfma_f32_16x16x32_f16(ah[mi], bf[ni], acc[mi][ni], 0, 0, 0);
            }
        }

        // --- score = ||c||^2 - 2*dot; running argmin (nt ascending => strict <) ---
#pragma unroll
        for (int ni = 0; ni < 4; ++ni) {
            const int c = c0 + wave_n * 64 + ni * 16 + lane15;
            const float nrm = nc[c];
#pragma unroll
            for (int mi = 0; mi < 4; ++mi)
#pragma unroll
                for (int r = 0; r < 4; ++r) {
                    const float v = fmaf(-2.0f, acc[mi][ni][r], nrm);
                    if (v < minv[mi][r]) { minv[mi][r] = v; mini[mi][r] = c; }
                }
        }
    }

    // --- block argmin reduction; write per-slice partial ---
    __syncthreads();
    float* redv = (float*)smem;            // [2 wave_n][128 rows][16 lanes]
    int*   redi = (int*)(smem + 16384);
#pragma unroll
    for (int mi = 0; mi < 4; ++mi)
#pragma unroll
        for (int r = 0; r < 4; ++r) {
            const int rl = wave_m * 64 + mi * 16 + quad * 4 + r;
            const int o = wave_n * 2048 + rl * 16 + lane15;
            redv[o] = minv[mi][r];
            redi[o] = mini[mi][r];
        }
    __syncthreads();
    if (tid < BMT) {
        float bv = __builtin_inff();
        int   bi = 0x7fffffff;
        for (int j = 0; j < 32; ++j) {
            const int o = (j >= 16 ? 2048 : 0) + tid * 16 + (j & 15);
            const float v = redv[o];
            const int   i = redi[o];
            if (v < bv || (v == bv && i < bi)) { bv = v; bi = i; }
        }
        partials[(size_t)(row0 + tid) * SLICES + ns] = make_float2(bv, __int_as_float(bi));
    }
}

// ---------------------------------------------------------------------------
// Kernel 3: merge slice partials -> final idx; gather z_q; loss partial.
// One wave per token; grid 8192 x 256.
__global__ void vq_merge_kernel(const float* __restrict__ z_e,
                                const float* __restrict__ cb,
                                const float2* __restrict__ partials,
                                float* __restrict__ out,
                                float* __restrict__ accum) {
    const int wid   = threadIdx.x >> 6;
    const int lane  = threadIdx.x & 63;
    const int token = blockIdx.x * 4 + wid;
    float bv = __builtin_inff();
    int   bi = 0;
    // slices hold ascending disjoint code ranges; strict < => lowest index on tie
#pragma unroll
    for (int s = 0; s < SLICES; ++s) {
        float2 p = partials[(size_t)token * SLICES + s];
        if (p.x < bv) { bv = p.x; bi = __float_as_int(p.y); }
    }
    const int code = bi & (N_CODES - 1);
    const float4* zp = (const float4*)(z_e + (size_t)token * DIM);
    const float4* cp = (const float4*)(cb + (size_t)code * DIM);
    float4* op = (float4*)out + (size_t)token * (DIM / 4);
    float s = 0.0f;
#pragma unroll
    for (int i = 0; i < 2; ++i) {
        const int e = lane + i * 64;
        float4 z = zp[e];
        float4 q = cp[e];
        op[e] = q;   // z_q_st value == z_q (exact fp32 codebook row)
        float dx = z.x - q.x, dy = z.y - q.y, dz = z.z - q.z, dw = z.w - q.w;
        s += dx * dx + dy * dy + dz * dz + dw * dw;
    }
#pragma unroll
    for (int off = 32; off > 0; off >>= 1) s += __shfl_down(s, off);
    if (lane == 0) {
        atomicAdd(accum, s);
        out[OUT_IDX + token] = (float)code;
    }
}

// ---------------------------------------------------------------------------
// Kernel 4: finalize losses
__global__ void vq_finalize_kernel(const float* __restrict__ accum,
                                   float* __restrict__ out) {
    const float c = *accum * (1.0f / (float)(N_TOKENS * DIM));
    out[OUT_VQ]     = 0.25f * c;
    out[OUT_COMMIT] = c;
}

// ---------------------------------------------------------------------------
extern "C" void kernel_launch(void* const* d_in, const int* in_sizes, int n_in,
                              void* d_out, int out_size, void* d_ws, size_t ws_size,
                              hipStream_t stream) {
    const float* z_e = (const float*)d_in[0];
    const float* cb  = (const float*)d_in[1];
    float* out = (float*)d_out;

    _Float16* cb_hi = (_Float16*)((char*)d_ws + WS_CBHI);
    _Float16* cb_lo = (_Float16*)((char*)d_ws + WS_CBLO);
    float*    nc    = (float*)((char*)d_ws + WS_NC);
    float2*   part  = (float2*)((char*)d_ws + WS_PART);
    float*    accum = (float*)((char*)d_ws + WS_ACC);

    hipLaunchKernelGGL(vq_prep_kernel, dim3(N_CODES / 4), dim3(256), 0, stream,
                       cb, cb_hi, cb_lo, nc, accum);
    hipLaunchKernelGGL(vq_main_kernel, dim3(N_TOKENS / BMT, SLICES), dim3(256), 0, stream,
                       z_e, cb_hi, cb_lo, nc, part);
    hipLaunchKernelGGL(vq_merge_kernel, dim3(N_TOKENS / 4), dim3(256), 0, stream,
                       z_e, cb, part, out, accum);
    hipLaunchKernelGGL(vq_finalize_kernel, dim3(1), dim3(1), 0, stream, accum, out);
}

// Round 5
// 1312.082 us; speedup vs baseline: 1.8747x; 1.6531x over previous
//
#include <hip/hip_runtime.h>

// Problem constants (fixed by the reference)
#define N_TOKENS 32768
#define N_CODES  8192
#define DIM      512

// Tiling: 128 token-rows x 128 codes per tile, BK=64, 4 code-slices
#define BMT 128
#define BNT 128
#define SLICES 4
#define SLICE_CODES (N_CODES / SLICES)   // 2048
#define NTILES (SLICE_CODES / BNT)       // 16
#define BK 64

// Output layout (FP32 elements, reference return order)
#define OUT_VQ     16777216
#define OUT_COMMIT 16777217
#define OUT_IDX    16777218

// Workspace byte offsets: cb_hi 8MB | cb_lo 8MB | nc 32KB | partials 1MB | accum
#define WS_CBHI 0
#define WS_CBLO 8388608
#define WS_NC   16777216
#define WS_PART 16809984
#define WS_ACC  17858560   // total ~17.03 MB (proven OK in round 4)

typedef _Float16 f16x8 __attribute__((ext_vector_type(8)));
typedef _Float16 f16x4 __attribute__((ext_vector_type(4)));
typedef float    f32x4 __attribute__((ext_vector_type(4)));

// XOR-swizzled LDS offset (halves) for (row, kgrp of 8 halves); row stride 128B.
// Conflict-clean (round 3/4: ~4e6 conflicts over ~2e9 LDS accesses).
__device__ __forceinline__ int sw_idx(int row, int kgrp) {
    return row * 64 + ((kgrp ^ (row & 7)) << 3);
}

// async 16B global->LDS (lds dest = wave-uniform base + lane*16)
__device__ __forceinline__ void async_copy16(void* lds, const void* g) {
    __builtin_amdgcn_global_load_lds(
        (const __attribute__((address_space(1))) unsigned int*)g,
        (__attribute__((address_space(3))) unsigned int*)lds,
        16, 0, 0);
}

// ---------------------------------------------------------------------------
// Kernel 1: codebook -> planar f16 hi/lo split + squared norms + zero accum.
__global__ void vq_prep_kernel(const float* __restrict__ cb,
                               _Float16* __restrict__ cb_hi,
                               _Float16* __restrict__ cb_lo,
                               float* __restrict__ nc,
                               float* __restrict__ accum) {
    if (blockIdx.x == 0 && threadIdx.x == 0) *accum = 0.0f;
    const int wid  = threadIdx.x >> 6;
    const int lane = threadIdx.x & 63;
    const int row  = blockIdx.x * 4 + wid;
    const float4* src = (const float4*)(cb + (size_t)row * DIM);
    float4 v0 = src[lane * 2];
    float4 v1 = src[lane * 2 + 1];
    float s = v0.x*v0.x + v0.y*v0.y + v0.z*v0.z + v0.w*v0.w
            + v1.x*v1.x + v1.y*v1.y + v1.z*v1.z + v1.w*v1.w;
    f16x8 hi = {(_Float16)v0.x, (_Float16)v0.y, (_Float16)v0.z, (_Float16)v0.w,
                (_Float16)v1.x, (_Float16)v1.y, (_Float16)v1.z, (_Float16)v1.w};
    f16x8 lo = {(_Float16)(v0.x - (float)hi[0]), (_Float16)(v0.y - (float)hi[1]),
                (_Float16)(v0.z - (float)hi[2]), (_Float16)(v0.w - (float)hi[3]),
                (_Float16)(v1.x - (float)hi[4]), (_Float16)(v1.y - (float)hi[5]),
                (_Float16)(v1.z - (float)hi[6]), (_Float16)(v1.w - (float)hi[7])};
    *(f16x8*)&cb_hi[(size_t)row * DIM + lane * 8] = hi;
    *(f16x8*)&cb_lo[(size_t)row * DIM + lane * 8] = lo;
#pragma unroll
    for (int off = 32; off > 0; off >>= 1) s += __shfl_down(s, off);
    if (lane == 0) nc[row] = s;
}

// ---------------------------------------------------------------------------
// Kernel 2: 3-plane f16-split GEMM + per-slice argmin.
// Grid (256 m-tiles, 4 slices) x 256 threads (2x2 waves of 64x64).
// Per k-chunk: ONE staging phase (async B-hi + async B-lo + A convert),
// TWO barriers, then 96 uninterrupted MFMAs (passes hh, lh, hl).
__global__ __launch_bounds__(256, 2)
void vq_main_kernel(const float* __restrict__ z_e,
                    const _Float16* __restrict__ cb_hi,
                    const _Float16* __restrict__ cb_lo,
                    const float* __restrict__ nc,
                    float2* __restrict__ partials) {
    // 64 KB LDS -> 2 blocks/CU
    __shared__ __align__(16) unsigned char smem[65536];
    _Float16* As_hi = (_Float16*)smem;             // 16KB: 128 rows x 64 k
    _Float16* As_lo = (_Float16*)(smem + 16384);   // 16KB
    _Float16* Bs_hi = (_Float16*)(smem + 32768);   // 16KB: 128 codes x 64 k
    _Float16* Bs_lo = (_Float16*)(smem + 49152);   // 16KB

    const int tid    = threadIdx.x;
    const int wid    = tid >> 6;
    const int lane   = tid & 63;
    const int wave_m = wid >> 1;
    const int wave_n = wid & 1;
    const int lane15 = lane & 15;
    const int quad   = lane >> 4;

    const int row0 = blockIdx.x * BMT;
    const int ns   = blockIdx.y;
    const int c00  = ns * SLICE_CODES;

    float minv[4][4];
    int   mini[4][4];
#pragma unroll
    for (int mi = 0; mi < 4; ++mi)
#pragma unroll
        for (int r = 0; r < 4; ++r) { minv[mi][r] = __builtin_inff(); mini[mi][r] = 0; }

    const int s_r0 = tid >> 4;    // A staging: 16 rows x 16 float4-groups
    const int s_cg = tid & 15;
    const int b_r8 = lane >> 3;   // B staging: 8 rows x 8 kgrps per wave-load
    const int b_g  = lane & 7;

#pragma unroll 1
    for (int nt = 0; nt < NTILES; ++nt) {
        const int c0 = c00 + nt * BNT;
        f32x4 acc[4][4];
#pragma unroll
        for (int mi = 0; mi < 4; ++mi)
#pragma unroll
            for (int ni = 0; ni < 4; ++ni) acc[mi][ni] = (f32x4){0.f, 0.f, 0.f, 0.f};

#pragma unroll 1
        for (int kc = 0; kc < DIM / BK; ++kc) {
            __syncthreads();   // previous chunk's readers done; LDS free
            // --- stage B hi+lo: 8 async wave-loads per wave, swizzled src ---
#pragma unroll
            for (int i = 0; i < 4; ++i) {
                const int L = wid * 4 + i;
                const int brow = L * 8 + b_r8;
                const size_t goff = (size_t)(c0 + brow) * DIM + kc * BK + ((b_g ^ (brow & 7)) << 3);
                async_copy16(Bs_hi + L * 512, cb_hi + goff);
                async_copy16(Bs_lo + L * 512, cb_lo + goff);
            }
            // --- stage A hi+lo from one fp32 read ---
#pragma unroll
            for (int rr = 0; rr < 8; ++rr) {
                const int row = rr * 16 + s_r0;
                float4 v = *(const float4*)&z_e[(size_t)(row0 + row) * DIM + kc * BK + s_cg * 4];
                f16x4 hi = {(_Float16)v.x, (_Float16)v.y, (_Float16)v.z, (_Float16)v.w};
                f16x4 lo = {(_Float16)(v.x - (float)hi[0]), (_Float16)(v.y - (float)hi[1]),
                            (_Float16)(v.z - (float)hi[2]), (_Float16)(v.w - (float)hi[3])};
                const int a = sw_idx(row, s_cg >> 1) + ((s_cg & 1) << 2);
                *(f16x4*)&As_hi[a] = hi;
                *(f16x4*)&As_lo[a] = lo;
            }
            __syncthreads();   // staging visible (single async-drain point)

            // --- compute: per ks load all 16 frags, then 48 MFMAs by pass ---
#pragma unroll
            for (int ks = 0; ks < 2; ++ks) {
                const int kg = ks * 4 + quad;
                f16x8 ah[4], al[4], bh[4], bl[4];
#pragma unroll
                for (int mi = 0; mi < 4; ++mi) {
                    const int a = sw_idx(wave_m * 64 + mi * 16 + lane15, kg);
                    ah[mi] = *(const f16x8*)&As_hi[a];
                    al[mi] = *(const f16x8*)&As_lo[a];
                }
#pragma unroll
                for (int ni = 0; ni < 4; ++ni) {
                    const int b = sw_idx(wave_n * 64 + ni * 16 + lane15, kg);
                    bh[ni] = *(const f16x8*)&Bs_hi[b];
                    bl[ni] = *(const f16x8*)&Bs_lo[b];
                }
                // pass 1: Ahi x Bhi (16 independent accs)
#pragma unroll
                for (int mi = 0; mi < 4; ++mi)
#pragma unroll
                    for (int ni = 0; ni < 4; ++ni)
                        acc[mi][ni] = __builtin_amdgcn_mfma_f32_16x16x32_f16(ah[mi], bh[ni], acc[mi][ni], 0, 0, 0);
                // pass 2: Alo x Bhi
#pragma unroll
                for (int mi = 0; mi < 4; ++mi)
#pragma unroll
                    for (int ni = 0; ni < 4; ++ni)
                        acc[mi][ni] = __builtin_amdgcn_mfma_f32_16x16x32_f16(al[mi], bh[ni], acc[mi][ni], 0, 0, 0);
                // pass 3: Ahi x Blo
#pragma unroll
                for (int mi = 0; mi < 4; ++mi)
#pragma unroll
                    for (int ni = 0; ni < 4; ++ni)
                        acc[mi][ni] = __builtin_amdgcn_mfma_f32_16x16x32_f16(ah[mi], bl[ni], acc[mi][ni], 0, 0, 0);
            }
        }

        // --- score = ||c||^2 - 2*dot; running argmin ---
#pragma unroll
        for (int ni = 0; ni < 4; ++ni) {
            const int c = c0 + wave_n * 64 + ni * 16 + lane15;
            const float nrm = nc[c];
#pragma unroll
            for (int mi = 0; mi < 4; ++mi)
#pragma unroll
                for (int r = 0; r < 4; ++r) {
                    const float v = fmaf(-2.0f, acc[mi][ni][r], nrm);
                    if (v < minv[mi][r]) { minv[mi][r] = v; mini[mi][r] = c; }
                }
        }
    }

    // --- block argmin reduction; write per-slice partial ---
    __syncthreads();
    float* redv = (float*)smem;            // [2 wave_n][128 rows][16 lanes]
    int*   redi = (int*)(smem + 16384);
#pragma unroll
    for (int mi = 0; mi < 4; ++mi)
#pragma unroll
        for (int r = 0; r < 4; ++r) {
            const int rl = wave_m * 64 + mi * 16 + quad * 4 + r;
            const int o = wave_n * 2048 + rl * 16 + lane15;
            redv[o] = minv[mi][r];
            redi[o] = mini[mi][r];
        }
    __syncthreads();
    if (tid < BMT) {
        float bv = __builtin_inff();
        int   bi = 0x7fffffff;
        for (int j = 0; j < 32; ++j) {
            const int o = (j >= 16 ? 2048 : 0) + tid * 16 + (j & 15);
            const float v = redv[o];
            const int   i = redi[o];
            if (v < bv || (v == bv && i < bi)) { bv = v; bi = i; }
        }
        partials[(size_t)(row0 + tid) * SLICES + ns] = make_float2(bv, __int_as_float(bi));
    }
}

// ---------------------------------------------------------------------------
// Kernel 3: merge slice partials -> final idx; gather z_q; loss partial.
__global__ void vq_merge_kernel(const float* __restrict__ z_e,
                                const float* __restrict__ cb,
                                const float2* __restrict__ partials,
                                float* __restrict__ out,
                                float* __restrict__ accum) {
    const int wid   = threadIdx.x >> 6;
    const int lane  = threadIdx.x & 63;
    const int token = blockIdx.x * 4 + wid;
    float bv = __builtin_inff();
    int   bi = 0;
    // slices hold ascending disjoint code ranges; strict < => lowest index on tie
#pragma unroll
    for (int s = 0; s < SLICES; ++s) {
        float2 p = partials[(size_t)token * SLICES + s];
        if (p.x < bv) { bv = p.x; bi = __float_as_int(p.y); }
    }
    const int code = bi & (N_CODES - 1);
    const float4* zp = (const float4*)(z_e + (size_t)token * DIM);
    const float4* cp = (const float4*)(cb + (size_t)code * DIM);
    float4* op = (float4*)out + (size_t)token * (DIM / 4);
    float s = 0.0f;
#pragma unroll
    for (int i = 0; i < 2; ++i) {
        const int e = lane + i * 64;
        float4 z = zp[e];
        float4 q = cp[e];
        op[e] = q;   // z_q_st value == z_q (exact fp32 codebook row)
        float dx = z.x - q.x, dy = z.y - q.y, dz = z.z - q.z, dw = z.w - q.w;
        s += dx * dx + dy * dy + dz * dz + dw * dw;
    }
#pragma unroll
    for (int off = 32; off > 0; off >>= 1) s += __shfl_down(s, off);
    if (lane == 0) {
        atomicAdd(accum, s);
        out[OUT_IDX + token] = (float)code;
    }
}

// ---------------------------------------------------------------------------
// Kernel 4: finalize losses
__global__ void vq_finalize_kernel(const float* __restrict__ accum,
                                   float* __restrict__ out) {
    const float c = *accum * (1.0f / (float)(N_TOKENS * DIM));
    out[OUT_VQ]     = 0.25f * c;
    out[OUT_COMMIT] = c;
}

// ---------------------------------------------------------------------------
extern "C" void kernel_launch(void* const* d_in, const int* in_sizes, int n_in,
                              void* d_out, int out_size, void* d_ws, size_t ws_size,
                              hipStream_t stream) {
    const float* z_e = (const float*)d_in[0];
    const float* cb  = (const float*)d_in[1];
    float* out = (float*)d_out;

    _Float16* cb_hi = (_Float16*)((char*)d_ws + WS_CBHI);
    _Float16* cb_lo = (_Float16*)((char*)d_ws + WS_CBLO);
    float*    nc    = (float*)((char*)d_ws + WS_NC);
    float2*   part  = (float2*)((char*)d_ws + WS_PART);
    float*    accum = (float*)((char*)d_ws + WS_ACC);

    hipLaunchKernelGGL(vq_prep_kernel, dim3(N_CODES / 4), dim3(256), 0, stream,
                       cb, cb_hi, cb_lo, nc, accum);
    hipLaunchKernelGGL(vq_main_kernel, dim3(N_TOKENS / BMT, SLICES), dim3(256), 0, stream,
                       z_e, cb_hi, cb_lo, nc, part);
    hipLaunchKernelGGL(vq_merge_kernel, dim3(N_TOKENS / 4), dim3(256), 0, stream,
                       z_e, cb, part, out, accum);
    hipLaunchKernelGGL(vq_finalize_kernel, dim3(1), dim3(1), 0, stream, accum, out);
}

// Round 6
// 845.308 us; speedup vs baseline: 2.9100x; 1.5522x over previous
//
#include <hip/hip_runtime.h>

// Problem constants (fixed by the reference)
#define N_TOKENS 32768
#define N_CODES  8192
#define DIM      512

// Tiling: 128 token-rows x 128 codes per tile, BK=64, 4 code-slices
#define BMT 128
#define BNT 128
#define SLICES 4
#define SLICE_CODES (N_CODES / SLICES)   // 2048
#define NTILES (SLICE_CODES / BNT)       // 16
#define BK 64

// Output layout (FP32 elements, reference return order)
#define OUT_VQ     16777216
#define OUT_COMMIT 16777217
#define OUT_IDX    16777218

// Workspace byte offsets
#define WS_CBHI 0                         //  8 MB codebook f16 hi
#define WS_CBLO 8388608                   //  8 MB codebook f16 lo
#define WS_NC   16777216                  // 32 KB code norms
#define WS_PART 16809984                  //  1 MB slice partials
#define WS_ACC  17858560                  //  4 B loss accum
#define WS_ZEHI 18874368                  // 32 MB z_e f16 hi
#define WS_ZELO 52428800                  // 32 MB z_e f16 lo
#define WS_NEED_FAST 85983232             // total for pre-split-A path

typedef _Float16 f16x8 __attribute__((ext_vector_type(8)));
typedef _Float16 f16x4 __attribute__((ext_vector_type(4)));
typedef float    f32x4 __attribute__((ext_vector_type(4)));

// XOR-swizzled LDS offset (halves) for (row, kgrp of 8 halves); row stride 128B.
// Conflict-clean (rounds 3-5: ~4e6 conflicts over ~2e9 LDS accesses).
__device__ __forceinline__ int sw_idx(int row, int kgrp) {
    return row * 64 + ((kgrp ^ (row & 7)) << 3);
}

// async 16B global->LDS (lds dest = wave-uniform base + lane*16)
__device__ __forceinline__ void async_copy16(void* lds, const void* g) {
    __builtin_amdgcn_global_load_lds(
        (const __attribute__((address_space(1))) unsigned int*)g,
        (__attribute__((address_space(3))) unsigned int*)lds,
        16, 0, 0);
}

// ---------------------------------------------------------------------------
// Kernel 1a: codebook -> planar f16 hi/lo + squared norms + zero accum.
__global__ void vq_prep_cb_kernel(const float* __restrict__ cb,
                                  _Float16* __restrict__ cb_hi,
                                  _Float16* __restrict__ cb_lo,
                                  float* __restrict__ nc,
                                  float* __restrict__ accum) {
    if (blockIdx.x == 0 && threadIdx.x == 0) *accum = 0.0f;
    const int wid  = threadIdx.x >> 6;
    const int lane = threadIdx.x & 63;
    const int row  = blockIdx.x * 4 + wid;
    const float4* src = (const float4*)(cb + (size_t)row * DIM);
    float4 v0 = src[lane * 2];
    float4 v1 = src[lane * 2 + 1];
    float s = v0.x*v0.x + v0.y*v0.y + v0.z*v0.z + v0.w*v0.w
            + v1.x*v1.x + v1.y*v1.y + v1.z*v1.z + v1.w*v1.w;
    f16x8 hi = {(_Float16)v0.x, (_Float16)v0.y, (_Float16)v0.z, (_Float16)v0.w,
                (_Float16)v1.x, (_Float16)v1.y, (_Float16)v1.z, (_Float16)v1.w};
    f16x8 lo = {(_Float16)(v0.x - (float)hi[0]), (_Float16)(v0.y - (float)hi[1]),
                (_Float16)(v0.z - (float)hi[2]), (_Float16)(v0.w - (float)hi[3]),
                (_Float16)(v1.x - (float)hi[4]), (_Float16)(v1.y - (float)hi[5]),
                (_Float16)(v1.z - (float)hi[6]), (_Float16)(v1.w - (float)hi[7])};
    *(f16x8*)&cb_hi[(size_t)row * DIM + lane * 8] = hi;
    *(f16x8*)&cb_lo[(size_t)row * DIM + lane * 8] = lo;
#pragma unroll
    for (int off = 32; off > 0; off >>= 1) s += __shfl_down(s, off);
    if (lane == 0) nc[row] = s;
}

// Kernel 1b: z_e -> planar f16 hi/lo (fast path only).
__global__ void vq_prep_ze_kernel(const float* __restrict__ z_e,
                                  _Float16* __restrict__ ze_hi,
                                  _Float16* __restrict__ ze_lo) {
    const int wid  = threadIdx.x >> 6;
    const int lane = threadIdx.x & 63;
    const int row  = blockIdx.x * 4 + wid;
    const float4* src = (const float4*)(z_e + (size_t)row * DIM);
    float4 v0 = src[lane * 2];
    float4 v1 = src[lane * 2 + 1];
    f16x8 hi = {(_Float16)v0.x, (_Float16)v0.y, (_Float16)v0.z, (_Float16)v0.w,
                (_Float16)v1.x, (_Float16)v1.y, (_Float16)v1.z, (_Float16)v1.w};
    f16x8 lo = {(_Float16)(v0.x - (float)hi[0]), (_Float16)(v0.y - (float)hi[1]),
                (_Float16)(v0.z - (float)hi[2]), (_Float16)(v0.w - (float)hi[3]),
                (_Float16)(v1.x - (float)hi[4]), (_Float16)(v1.y - (float)hi[5]),
                (_Float16)(v1.z - (float)hi[6]), (_Float16)(v1.w - (float)hi[7])};
    *(f16x8*)&ze_hi[(size_t)row * DIM + lane * 8] = hi;
    *(f16x8*)&ze_lo[(size_t)row * DIM + lane * 8] = lo;
}

// ---------------------------------------------------------------------------
// Kernel 2: 3-plane f16-split GEMM + per-slice argmin.
// Grid (256 m-tiles, 4 slices) x 256 threads (2x2 waves of 64x64).
// PRESPLIT=true: A and B both staged via async global_load_lds (zero convert
// VALU in the k-loop). PRESPLIT=false: round-5 in-kernel A convert fallback.
template <bool PRESPLIT>
__global__ __launch_bounds__(256, 2)
void vq_main_kernel(const float* __restrict__ z_e,
                    const _Float16* __restrict__ ze_hi,
                    const _Float16* __restrict__ ze_lo,
                    const _Float16* __restrict__ cb_hi,
                    const _Float16* __restrict__ cb_lo,
                    const float* __restrict__ nc,
                    float2* __restrict__ partials) {
    // 64 KB LDS -> 2 blocks/CU
    __shared__ __align__(16) unsigned char smem[65536];
    _Float16* As_hi = (_Float16*)smem;             // 16KB: 128 rows x 64 k
    _Float16* As_lo = (_Float16*)(smem + 16384);   // 16KB
    _Float16* Bs_hi = (_Float16*)(smem + 32768);   // 16KB: 128 codes x 64 k
    _Float16* Bs_lo = (_Float16*)(smem + 49152);   // 16KB

    const int tid    = threadIdx.x;
    const int wid    = tid >> 6;
    const int lane   = tid & 63;
    const int wave_m = wid >> 1;
    const int wave_n = wid & 1;
    const int lane15 = lane & 15;
    const int quad   = lane >> 4;

    const int row0 = blockIdx.x * BMT;
    const int ns   = blockIdx.y;
    const int c00  = ns * SLICE_CODES;

    float minv[4][4];
    int   mini[4][4];
#pragma unroll
    for (int mi = 0; mi < 4; ++mi)
#pragma unroll
        for (int r = 0; r < 4; ++r) { minv[mi][r] = __builtin_inff(); mini[mi][r] = 0; }

    const int s_r0 = tid >> 4;    // fallback A staging coords
    const int s_cg = tid & 15;
    const int b_r8 = lane >> 3;   // async staging: 8 rows x 8 kgrps per wave-load
    const int b_g  = lane & 7;

#pragma unroll 1
    for (int nt = 0; nt < NTILES; ++nt) {
        const int c0 = c00 + nt * BNT;
        f32x4 acc[4][4];
#pragma unroll
        for (int mi = 0; mi < 4; ++mi)
#pragma unroll
            for (int ni = 0; ni < 4; ++ni) acc[mi][ni] = (f32x4){0.f, 0.f, 0.f, 0.f};

#pragma unroll 1
        for (int kc = 0; kc < DIM / BK; ++kc) {
            __syncthreads();   // previous chunk's readers done; LDS free
            // --- stage B hi+lo: async, inverse-swizzled source ---
#pragma unroll
            for (int i = 0; i < 4; ++i) {
                const int L = wid * 4 + i;
                const int brow = L * 8 + b_r8;
                const size_t goff = (size_t)(c0 + brow) * DIM + kc * BK + ((b_g ^ (brow & 7)) << 3);
                async_copy16(Bs_hi + L * 512, cb_hi + goff);
                async_copy16(Bs_lo + L * 512, cb_lo + goff);
            }
            if constexpr (PRESPLIT) {
                // --- stage A hi+lo: async from pre-split planes ---
#pragma unroll
                for (int i = 0; i < 4; ++i) {
                    const int L = wid * 4 + i;
                    const int arow = L * 8 + b_r8;
                    const size_t goff = (size_t)(row0 + arow) * DIM + kc * BK + ((b_g ^ (arow & 7)) << 3);
                    async_copy16(As_hi + L * 512, ze_hi + goff);
                    async_copy16(As_lo + L * 512, ze_lo + goff);
                }
            } else {
                // --- fallback: stage A hi+lo from one fp32 read ---
#pragma unroll
                for (int rr = 0; rr < 8; ++rr) {
                    const int row = rr * 16 + s_r0;
                    float4 v = *(const float4*)&z_e[(size_t)(row0 + row) * DIM + kc * BK + s_cg * 4];
                    f16x4 hi = {(_Float16)v.x, (_Float16)v.y, (_Float16)v.z, (_Float16)v.w};
                    f16x4 lo = {(_Float16)(v.x - (float)hi[0]), (_Float16)(v.y - (float)hi[1]),
                                (_Float16)(v.z - (float)hi[2]), (_Float16)(v.w - (float)hi[3])};
                    const int a = sw_idx(row, s_cg >> 1) + ((s_cg & 1) << 2);
                    *(f16x4*)&As_hi[a] = hi;
                    *(f16x4*)&As_lo[a] = lo;
                }
            }
            __syncthreads();   // single async-drain point

            // --- compute: per ks load all 16 frags, then 48 MFMAs by pass ---
#pragma unroll
            for (int ks = 0; ks < 2; ++ks) {
                const int kg = ks * 4 + quad;
                f16x8 ah[4], al[4], bh[4], bl[4];
#pragma unroll
                for (int mi = 0; mi < 4; ++mi) {
                    const int a = sw_idx(wave_m * 64 + mi * 16 + lane15, kg);
                    ah[mi] = *(const f16x8*)&As_hi[a];
                    al[mi] = *(const f16x8*)&As_lo[a];
                }
#pragma unroll
                for (int ni = 0; ni < 4; ++ni) {
                    const int b = sw_idx(wave_n * 64 + ni * 16 + lane15, kg);
                    bh[ni] = *(const f16x8*)&Bs_hi[b];
                    bl[ni] = *(const f16x8*)&Bs_lo[b];
                }
                // pass 1: Ahi x Bhi (16 independent accumulators)
#pragma unroll
                for (int mi = 0; mi < 4; ++mi)
#pragma unroll
                    for (int ni = 0; ni < 4; ++ni)
                        acc[mi][ni] = __builtin_amdgcn_mfma_f32_16x16x32_f16(ah[mi], bh[ni], acc[mi][ni], 0, 0, 0);
                // pass 2: Alo x Bhi
#pragma unroll
                for (int mi = 0; mi < 4; ++mi)
#pragma unroll
                    for (int ni = 0; ni < 4; ++ni)
                        acc[mi][ni] = __builtin_amdgcn_mfma_f32_16x16x32_f16(al[mi], bh[ni], acc[mi][ni], 0, 0, 0);
                // pass 3: Ahi x Blo
#pragma unroll
                for (int mi = 0; mi < 4; ++mi)
#pragma unroll
                    for (int ni = 0; ni < 4; ++ni)
                        acc[mi][ni] = __builtin_amdgcn_mfma_f32_16x16x32_f16(ah[mi], bl[ni], acc[mi][ni], 0, 0, 0);
            }
        }

        // --- score = ||c||^2 - 2*dot; running argmin ---
#pragma unroll
        for (int ni = 0; ni < 4; ++ni) {
            const int c = c0 + wave_n * 64 + ni * 16 + lane15;
            const float nrm = nc[c];
#pragma unroll
            for (int mi = 0; mi < 4; ++mi)
#pragma unroll
                for (int r = 0; r < 4; ++r) {
                    const float v = fmaf(-2.0f, acc[mi][ni][r], nrm);
                    if (v < minv[mi][r]) { minv[mi][r] = v; mini[mi][r] = c; }
                }
        }
    }

    // --- block argmin reduction; write per-slice partial ---
    __syncthreads();
    float* redv = (float*)smem;            // [2 wave_n][128 rows][16 lanes]
    int*   redi = (int*)(smem + 16384);
#pragma unroll
    for (int mi = 0; mi < 4; ++mi)
#pragma unroll
        for (int r = 0; r < 4; ++r) {
            const int rl = wave_m * 64 + mi * 16 + quad * 4 + r;
            const int o = wave_n * 2048 + rl * 16 + lane15;
            redv[o] = minv[mi][r];
            redi[o] = mini[mi][r];
        }
    __syncthreads();
    if (tid < BMT) {
        float bv = __builtin_inff();
        int   bi = 0x7fffffff;
        for (int j = 0; j < 32; ++j) {
            const int o = (j >= 16 ? 2048 : 0) + tid * 16 + (j & 15);
            const float v = redv[o];
            const int   i = redi[o];
            if (v < bv || (v == bv && i < bi)) { bv = v; bi = i; }
        }
        partials[(size_t)(row0 + tid) * SLICES + ns] = make_float2(bv, __int_as_float(bi));
    }
}

// ---------------------------------------------------------------------------
// Kernel 3: merge slice partials -> final idx; gather z_q; loss partial.
// Grid 512 x 256: each wave handles 16 tokens; ONE atomic per block
// (512 total vs 32768 same-address atomics in rounds 4-5).
__global__ void vq_merge_kernel(const float* __restrict__ z_e,
                                const float* __restrict__ cb,
                                const float2* __restrict__ partials,
                                float* __restrict__ out,
                                float* __restrict__ accum) {
    __shared__ float wpart[4];
    const int wid  = threadIdx.x >> 6;
    const int lane = threadIdx.x & 63;
    const int tbase = blockIdx.x * 64 + wid * 16;
    float part = 0.0f;
#pragma unroll 1
    for (int t = 0; t < 16; ++t) {
        const int token = tbase + t;
        float bv = __builtin_inff();
        int   bi = 0;
        // slices hold ascending disjoint code ranges; strict < => lowest index on tie
#pragma unroll
        for (int s = 0; s < SLICES; ++s) {
            float2 p = partials[(size_t)token * SLICES + s];  // wave-uniform -> broadcast
            if (p.x < bv) { bv = p.x; bi = __float_as_int(p.y); }
        }
        const int code = bi & (N_CODES - 1);
        const float4* zp = (const float4*)(z_e + (size_t)token * DIM);
        const float4* cp = (const float4*)(cb + (size_t)code * DIM);
        float4* op = (float4*)out + (size_t)token * (DIM / 4);
#pragma unroll
        for (int i = 0; i < 2; ++i) {
            const int e = lane + i * 64;
            float4 z = zp[e];
            float4 q = cp[e];
            op[e] = q;   // z_q_st value == z_q (exact fp32 codebook row)
            float dx = z.x - q.x, dy = z.y - q.y, dz = z.z - q.z, dw = z.w - q.w;
            part += dx * dx + dy * dy + dz * dz + dw * dw;
        }
        if (lane == 0) out[OUT_IDX + token] = (float)code;
    }
#pragma unroll
    for (int off = 32; off > 0; off >>= 1) part += __shfl_down(part, off);
    if (lane == 0) wpart[wid] = part;
    __syncthreads();
    if (threadIdx.x == 0) atomicAdd(accum, wpart[0] + wpart[1] + wpart[2] + wpart[3]);
}

// ---------------------------------------------------------------------------
// Kernel 4: finalize losses
__global__ void vq_finalize_kernel(const float* __restrict__ accum,
                                   float* __restrict__ out) {
    const float c = *accum * (1.0f / (float)(N_TOKENS * DIM));
    out[OUT_VQ]     = 0.25f * c;
    out[OUT_COMMIT] = c;
}

// ---------------------------------------------------------------------------
extern "C" void kernel_launch(void* const* d_in, const int* in_sizes, int n_in,
                              void* d_out, int out_size, void* d_ws, size_t ws_size,
                              hipStream_t stream) {
    const float* z_e = (const float*)d_in[0];
    const float* cb  = (const float*)d_in[1];
    float* out = (float*)d_out;

    _Float16* cb_hi = (_Float16*)((char*)d_ws + WS_CBHI);
    _Float16* cb_lo = (_Float16*)((char*)d_ws + WS_CBLO);
    float*    nc    = (float*)((char*)d_ws + WS_NC);
    float2*   part  = (float2*)((char*)d_ws + WS_PART);
    float*    accum = (float*)((char*)d_ws + WS_ACC);
    _Float16* ze_hi = (_Float16*)((char*)d_ws + WS_ZEHI);
    _Float16* ze_lo = (_Float16*)((char*)d_ws + WS_ZELO);

    const bool fast = (ws_size >= (size_t)WS_NEED_FAST);  // call-invariant -> graph-safe

    hipLaunchKernelGGL(vq_prep_cb_kernel, dim3(N_CODES / 4), dim3(256), 0, stream,
                       cb, cb_hi, cb_lo, nc, accum);
    if (fast) {
        hipLaunchKernelGGL(vq_prep_ze_kernel, dim3(N_TOKENS / 4), dim3(256), 0, stream,
                           z_e, ze_hi, ze_lo);
        hipLaunchKernelGGL((vq_main_kernel<true>), dim3(N_TOKENS / BMT, SLICES), dim3(256), 0, stream,
                           z_e, ze_hi, ze_lo, cb_hi, cb_lo, nc, part);
    } else {
        hipLaunchKernelGGL((vq_main_kernel<false>), dim3(N_TOKENS / BMT, SLICES), dim3(256), 0, stream,
                           z_e, ze_hi, ze_lo, cb_hi, cb_lo, nc, part);
    }
    hipLaunchKernelGGL(vq_merge_kernel, dim3(N_TOKENS / 64), dim3(256), 0, stream,
                       z_e, cb, part, out, accum);
    hipLaunchKernelGGL(vq_finalize_kernel, dim3(1), dim3(1), 0, stream, accum, out);
}